// Round 7
// baseline (5235.312 us; speedup 1.0000x reference)
//
#include <hip/hip_runtime.h>
#include <hip/hip_fp16.h>

typedef _Float16 f16;
typedef _Float16 f16x2 __attribute__((ext_vector_type(2)));
typedef _Float16 f16x8 __attribute__((ext_vector_type(8)));
typedef float f32x4 __attribute__((ext_vector_type(4)));
typedef unsigned int u32;

#define BATCH 32
#define SEQT  2048
#define DIN   256
#define HU    256
#define G4    1024          // 4*H
#define MROWS (BATCH*SEQT)  // 65536

// ---- workspace layout (bytes) ----
#define WS_XW 0
#define WS_XH 134217728UL
#define WS_WT 167772160UL
#define WS_UP 168296448UL
#define WS_HX 168820736UL   // h-half exchange: [32][2][64] u32 = 16384
#define WS_FLG 168837120UL  // flags: 64 ints x 16-dword stride = 4096
#define WS_NEED 168841216UL

// ---------------- prep kernels ----------------
__global__ void pack_u(const float* __restrict__ U, u32* __restrict__ upk) {
    int idx = blockIdx.x * 256 + threadIdx.x;      // 128*1024
    int p = idx >> 10, j = idx & 1023;
    f16x2 h;
    h.x = (f16)U[(2 * p) * G4 + j];
    h.y = (f16)U[(2 * p + 1) * G4 + j];
    upk[p * G4 + j] = __builtin_bit_cast(u32, h);
}

__global__ void conv_x(const float* __restrict__ x, f16* __restrict__ xh) {
    int idx = blockIdx.x * 256 + threadIdx.x;      // 65536*32
    int row = idx >> 5, c = idx & 31;
    const float4* src = (const float4*)(x + row * 256 + c * 8);
    float4 v0 = src[0], v1 = src[1];
    f16x8 o;
    o[0] = (f16)v0.x; o[1] = (f16)v0.y; o[2] = (f16)v0.z; o[3] = (f16)v0.w;
    o[4] = (f16)v1.x; o[5] = (f16)v1.y; o[6] = (f16)v1.z; o[7] = (f16)v1.w;
    *(f16x8*)(xh + row * 256 + c * 8) = o;
}

__global__ void conv_w(const float* __restrict__ W, f16* __restrict__ wt) {
    int idx = blockIdx.x * 256 + threadIdx.x;      // 1024*32
    int j = idx >> 5, c = idx & 31;
    f16x8 o;
#pragma unroll
    for (int i = 0; i < 8; ++i) o[i] = (f16)W[(c * 8 + i) * G4 + j];
    *(f16x8*)(wt + j * 256 + c * 8) = o;
}

// ---------------- xW GEMM: [65536,256]x[256,1024] fp16 MFMA ----------------
__launch_bounds__(256)
__global__ void gemm_xw(const f16* __restrict__ xh, const f16* __restrict__ wt,
                        const float* __restrict__ bias, f16* __restrict__ xw) {
    __shared__ __align__(16) f16 As[128 * 256];   // 64 KB, swizzled chunks
    __shared__ __align__(16) f16 Bs[128 * 256];   // 64 KB
    int mt = blockIdx.x, nt = blockIdx.y;
    int t = threadIdx.x, lane = t & 63, w = t >> 6;

    const uint4* Ag = (const uint4*)(xh + (size_t)mt * 128 * 256);
    const uint4* Bg = (const uint4*)(wt + (size_t)nt * 128 * 256);
#pragma unroll
    for (int i = 0; i < 16; ++i) {
        int o16 = t + i * 256;            // 16B chunk id 0..4095
        int row = o16 >> 5, c = o16 & 31;
        uint4 va = Ag[o16];
        uint4 vb = Bg[o16];
        int sw = c ^ (row & 7);
        *(uint4*)((char*)As + row * 512 + sw * 16) = va;
        *(uint4*)((char*)Bs + row * 512 + sw * 16) = vb;
    }
    __syncthreads();

    int wr = w >> 1, wc = w & 1;
    f32x4 acc[4][4];
#pragma unroll
    for (int mi = 0; mi < 4; ++mi)
#pragma unroll
        for (int ni = 0; ni < 4; ++ni) acc[mi][ni] = (f32x4){0.f, 0.f, 0.f, 0.f};

    int rA = lane & 15;
    int kg = lane >> 4;    // 0..3 -> k-offset group of 8
#pragma unroll
    for (int ks = 0; ks < 8; ++ks) {
        f16x8 af[4], bf[4];
#pragma unroll
        for (int mi = 0; mi < 4; ++mi) {
            int row = wr * 64 + mi * 16 + rA;
            int c = ks * 4 + kg;
            af[mi] = *(const f16x8*)((const char*)As + row * 512 + ((c ^ (row & 7)) * 16));
        }
#pragma unroll
        for (int ni = 0; ni < 4; ++ni) {
            int row = wc * 64 + ni * 16 + rA;
            int c = ks * 4 + kg;
            bf[ni] = *(const f16x8*)((const char*)Bs + row * 512 + ((c ^ (row & 7)) * 16));
        }
#pragma unroll
        for (int mi = 0; mi < 4; ++mi)
#pragma unroll
            for (int ni = 0; ni < 4; ++ni)
                acc[mi][ni] = __builtin_amdgcn_mfma_f32_16x16x32_f16(af[mi], bf[ni], acc[mi][ni], 0, 0, 0);
    }

    // epilogue: C/D layout col=lane&15, row=(lane>>4)*4+q
    int r4 = (lane >> 4) * 4, cc = lane & 15;
    float bv[4];
#pragma unroll
    for (int ni = 0; ni < 4; ++ni) bv[ni] = bias[nt * 128 + wc * 64 + ni * 16 + cc];
#pragma unroll
    for (int mi = 0; mi < 4; ++mi)
#pragma unroll
        for (int ni = 0; ni < 4; ++ni)
#pragma unroll
            for (int q = 0; q < 4; ++q) {
                int grow = mt * 128 + wr * 64 + mi * 16 + r4 + q;
                int gcol = nt * 128 + wc * 64 + ni * 16 + cc;
                xw[(size_t)grow * 1024 + gcol] = (f16)(acc[mi][ni][q] + bv[ni]);
            }
}

// ---------------- recurrence ----------------
__device__ __forceinline__ float fdot2u(u32 u, u32 h, float acc) {
    return __builtin_amdgcn_fdot2(__builtin_bit_cast(f16x2, u),
                                  __builtin_bit_cast(f16x2, h), acc, false);
}
__device__ __forceinline__ float sigm(float x) {
    return 1.0f / (1.0f + __expf(-x));
}
__device__ __forceinline__ float tanh_f(float x) {
    x = fminf(fmaxf(x, -15.0f), 15.0f);
    float e = __expf(2.0f * x);
    return (e - 1.0f) / (e + 1.0f);
}

// ---- R7: 2 WGs per batch, U fully resident (regs+LDS), h-half exchange ----
// Evidence R1-R6: backend grants exactly 65536/blockDim VGPRs (512->128,
// 1024->64) no matter what attributes say; U bytes are single-consumer so
// they must be HELD in regs+LDS or re-stream every step. At 512 thr the
// grant is 128: one column/thread (128 U-pairs: 92 reg + 36 LDS) fits.
// Each WG owns 128 units (4 gates x 128 = 512 cols). Per step the two
// halves exchange 256 B of h via ws + agent-scope flags (cross-XCD safe);
// the exchange RT hides under the own-half MAC phase. Flags/hx are
// memset to 0 on the launch stream each call (replay-safe, monotone flags).

#define DECLC(c) uint4 uc_##c;
#define LOADP(c, pb) do {                              \
    uc_##c.x = upk[((pb)+4*(c)+0)*1024 + col];         \
    uc_##c.y = upk[((pb)+4*(c)+1)*1024 + col];         \
    uc_##c.z = upk[((pb)+4*(c)+2)*1024 + col];         \
    uc_##c.w = upk[((pb)+4*(c)+3)*1024 + col];         \
} while (0)
#define CHP(c, hb) do {                                \
    uint4 hv = *(const uint4*)&hpair[(hb) + 4*(c)];    \
    a0 = fdot2u(uc_##c.x, hv.x, a0);                   \
    a1 = fdot2u(uc_##c.y, hv.y, a1);                   \
    a2 = fdot2u(uc_##c.z, hv.z, a2);                   \
    a3 = fdot2u(uc_##c.w, hv.w, a3);                   \
} while (0)

__launch_bounds__(512)
__global__ void lstm_rec(const u32* __restrict__ upk, const f16* __restrict__ xw,
                         float* __restrict__ out, u32* hx, int* flg) {
    __shared__ __align__(16) u32 ulds[512 * 36];   // 73728 B: partner pairs 28..63
    __shared__ __align__(16) u32 hpair[128];       // full h as 128 f16-pairs (pair p = units 2p,2p+1)
    __shared__ __align__(16) float gbuf[512];      // activated gates

    int wg = blockIdx.x, b = wg >> 1, half = wg & 1;
    int t = threadIdx.x;
    int col = (t >> 7) * 256 + half * 128 + (t & 127);  // gate=t>>7, unit=half*128+(t&127)

    const int pown = half * 64;          // own-k pair base (our 128 units)
    const int ppart = (1 - half) * 64;   // partner-k pair base

    // U in registers: own-k pairs pown+0..63 (chunks 0..15),
    // partner-k pairs ppart+0..27 (chunks 16..22); pairs ppart+28..63 in LDS.
    DECLC(0)  DECLC(1)  DECLC(2)  DECLC(3)  DECLC(4)  DECLC(5)
    DECLC(6)  DECLC(7)  DECLC(8)  DECLC(9)  DECLC(10) DECLC(11)
    DECLC(12) DECLC(13) DECLC(14) DECLC(15) DECLC(16) DECLC(17)
    DECLC(18) DECLC(19) DECLC(20) DECLC(21) DECLC(22)

    LOADP(0, pown);  LOADP(1, pown);  LOADP(2, pown);  LOADP(3, pown);
    LOADP(4, pown);  LOADP(5, pown);  LOADP(6, pown);  LOADP(7, pown);
    LOADP(8, pown);  LOADP(9, pown);  LOADP(10, pown); LOADP(11, pown);
    LOADP(12, pown); LOADP(13, pown); LOADP(14, pown); LOADP(15, pown);
    LOADP(16, ppart - 64); LOADP(17, ppart - 64); LOADP(18, ppart - 64);
    LOADP(19, ppart - 64); LOADP(20, ppart - 64); LOADP(21, ppart - 64);
    LOADP(22, ppart - 64);   // chunks 16..22 -> pairs ppart + 0..27

#pragma unroll
    for (int i = 0; i < 36; ++i)
        ulds[t * 36 + i] = upk[(ppart + 28 + i) * 1024 + col];
    if (t < 128) hpair[t] = 0u;

    u32* hx_own  = hx + (size_t)(b * 2 + half) * 64;
    u32* hx_part = hx + (size_t)(b * 2 + 1 - half) * 64;
    int* flg_own  = flg + (b * 2 + half) * 16;
    int* flg_part = flg + (b * 2 + 1 - half) * 16;

    float c_state = 0.0f;
    const f16* xp = xw + (size_t)b * SEQT * G4;
    float* op = out + (size_t)b * SEQT * HU + half * 128;
    f16 xa = xp[col];
    __syncthreads();

    for (int st = 0; st < SEQT; ++st) {
        float a0 = (float)xa, a1 = 0.f, a2 = 0.f, a3 = 0.f;
        if (st < SEQT - 1) xa = xp[G4 + col];
        xp += G4;

        // ---- A: own-k MACs (local h half; hides the exchange RT) ----
        CHP(0, pown);  CHP(1, pown);  CHP(2, pown);  CHP(3, pown);
        CHP(4, pown);  CHP(5, pown);  CHP(6, pown);  CHP(7, pown);
        CHP(8, pown);  CHP(9, pown);  CHP(10, pown); CHP(11, pown);
        CHP(12, pown); CHP(13, pown); CHP(14, pown); CHP(15, pown);

        // ---- B: wait for partner h(st-1), pull 256 B into LDS ----
        if (t == 0) {
            int spins = 0;
            while (__hip_atomic_load(flg_part, __ATOMIC_ACQUIRE,
                                     __HIP_MEMORY_SCOPE_AGENT) < st &&
                   spins < (1 << 22)) {
                __builtin_amdgcn_s_sleep(2);
                ++spins;
            }
        }
        __syncthreads();
        if (t < 64)
            hpair[ppart + t] = __hip_atomic_load(hx_part + t, __ATOMIC_RELAXED,
                                                 __HIP_MEMORY_SCOPE_AGENT);
        __syncthreads();

        // ---- C: partner-k MACs ----
        CHP(16, ppart - 64); CHP(17, ppart - 64); CHP(18, ppart - 64);
        CHP(19, ppart - 64); CHP(20, ppart - 64); CHP(21, ppart - 64);
        CHP(22, ppart - 64);
#pragma unroll
        for (int ch = 0; ch < 9; ++ch) {
            uint4 hv = *(const uint4*)&hpair[ppart + 28 + ch * 4];
            uint4 u4 = *(const uint4*)&ulds[t * 36 + ch * 4];
            a0 = fdot2u(u4.x, hv.x, a0);
            a1 = fdot2u(u4.y, hv.y, a1);
            a2 = fdot2u(u4.z, hv.z, a2);
            a3 = fdot2u(u4.w, hv.w, a3);
        }
        float a = (a0 + a1) + (a2 + a3);

        // gate = t>>7 (wave-uniform): 0=i 1=f 2=g 3=o
        float act = ((t >> 7) == 2) ? tanh_f(a) : sigm(a);
        gbuf[t] = act;
        __syncthreads();

        // ---- D: c/h update for own 128 units ----
        if (t < 128) {
            float gi = gbuf[t];
            float gf = gbuf[128 + t];
            float gg = gbuf[256 + t];
            float go = gbuf[384 + t];
            c_state = gf * c_state + gi * gg;
            float h = go * tanh_f(c_state);
            op[t] = h;
            ((f16*)hpair)[half * 128 + t] = (f16)h;
        }
        op += HU;
        __syncthreads();

        // ---- E: publish own h-half + flag ----
        if (t < 64)
            __hip_atomic_store(hx_own + t, hpair[pown + t], __ATOMIC_RELAXED,
                               __HIP_MEMORY_SCOPE_AGENT);
        __syncthreads();
        if (t == 0)
            __hip_atomic_store(flg_own, st + 1, __ATOMIC_RELEASE,
                               __HIP_MEMORY_SCOPE_AGENT);
    }
}

extern "C" void kernel_launch(void* const* d_in, const int* in_sizes, int n_in,
                              void* d_out, int out_size, void* d_ws, size_t ws_size,
                              hipStream_t stream) {
    const float* x    = (const float*)d_in[0];
    const float* W    = (const float*)d_in[1];
    const float* U    = (const float*)d_in[2];
    const float* bias = (const float*)d_in[3];
    float* out = (float*)d_out;

    if (ws_size < WS_NEED) return;  // fail loudly rather than corrupt
    char* ws = (char*)d_ws;
    f16* xw  = (f16*)(ws + WS_XW);
    f16* xh  = (f16*)(ws + WS_XH);
    f16* wt  = (f16*)(ws + WS_WT);
    u32* upk = (u32*)(ws + WS_UP);
    u32* hx  = (u32*)(ws + WS_HX);
    int* flg = (int*)(ws + WS_FLG);

    // zero exchange buffers + flags every call (replay-safe; graph-capturable)
    hipMemsetAsync(ws + WS_HX, 0, WS_NEED - WS_HX, stream);

    pack_u<<<512, 256, 0, stream>>>(U, upk);
    conv_x<<<8192, 256, 0, stream>>>(x, xh);
    conv_w<<<128, 256, 0, stream>>>(W, wt);
    gemm_xw<<<dim3(512, 8), 256, 0, stream>>>(xh, wt, bias, xw);
    lstm_rec<<<64, 512, 0, stream>>>(upk, xw, out, hx, flg);
}

// Round 8
// 4155.887 us; speedup vs baseline: 1.2597x; 1.2597x over previous
//
#include <hip/hip_runtime.h>
#include <hip/hip_fp16.h>

typedef _Float16 f16;
typedef _Float16 f16x2 __attribute__((ext_vector_type(2)));
typedef _Float16 f16x8 __attribute__((ext_vector_type(8)));
typedef float f32x4 __attribute__((ext_vector_type(4)));
typedef unsigned int u32;

#define BATCH 32
#define SEQT  2048
#define DIN   256
#define HU    256
#define G4    1024          // 4*H
#define MROWS (BATCH*SEQT)  // 65536

// ---- workspace layout (bytes) ----
// xw   f16 [65536][1024] @ 0            134217728
// xh   f16 [65536][256]  @ 134217728     33554432
// wt   f16 [1024][256]   @ 167772160       524288
// upk4 u32 [32][1024][4] @ 168296448       524288   (chunk-major U)
#define WS_XW 0
#define WS_XH 134217728UL
#define WS_WT 167772160UL
#define WS_UP 168296448UL
#define WS_NEED 168820736UL

// ---------------- prep kernels ----------------
// upk4 chunk-major: chunk c (= pairs 4c..4c+3), col j, sub-dword d=p&3
// lives at dword index (c*1024 + j)*4 + d. A thread's uint4 chunk load
// upk4[c*1024 + t] is 16 B at byte (c*1024+t)*16 -> consecutive lanes
// read consecutive 16 B => one coalesced global_load_dwordx4 per chunk.
__global__ void pack_u(const float* __restrict__ U, u32* __restrict__ upk4) {
    int idx = blockIdx.x * 256 + threadIdx.x;      // 128*1024
    int p = idx >> 10, j = idx & 1023;
    f16x2 h;
    h.x = (f16)U[(2 * p) * G4 + j];
    h.y = (f16)U[(2 * p + 1) * G4 + j];
    upk4[(((p >> 2) * 1024 + j) << 2) + (p & 3)] = __builtin_bit_cast(u32, h);
}

__global__ void conv_x(const float* __restrict__ x, f16* __restrict__ xh) {
    int idx = blockIdx.x * 256 + threadIdx.x;      // 65536*32
    int row = idx >> 5, c = idx & 31;
    const float4* src = (const float4*)(x + row * 256 + c * 8);
    float4 v0 = src[0], v1 = src[1];
    f16x8 o;
    o[0] = (f16)v0.x; o[1] = (f16)v0.y; o[2] = (f16)v0.z; o[3] = (f16)v0.w;
    o[4] = (f16)v1.x; o[5] = (f16)v1.y; o[6] = (f16)v1.z; o[7] = (f16)v1.w;
    *(f16x8*)(xh + row * 256 + c * 8) = o;
}

__global__ void conv_w(const float* __restrict__ W, f16* __restrict__ wt) {
    int idx = blockIdx.x * 256 + threadIdx.x;      // 1024*32
    int j = idx >> 5, c = idx & 31;
    f16x8 o;
#pragma unroll
    for (int i = 0; i < 8; ++i) o[i] = (f16)W[(c * 8 + i) * G4 + j];
    *(f16x8*)(wt + j * 256 + c * 8) = o;
}

// ---------------- xW GEMM: [65536,256]x[256,1024] fp16 MFMA ----------------
__launch_bounds__(256)
__global__ void gemm_xw(const f16* __restrict__ xh, const f16* __restrict__ wt,
                        const float* __restrict__ bias, f16* __restrict__ xw) {
    __shared__ __align__(16) f16 As[128 * 256];   // 64 KB, swizzled chunks
    __shared__ __align__(16) f16 Bs[128 * 256];   // 64 KB
    int mt = blockIdx.x, nt = blockIdx.y;
    int t = threadIdx.x, lane = t & 63, w = t >> 6;

    const uint4* Ag = (const uint4*)(xh + (size_t)mt * 128 * 256);
    const uint4* Bg = (const uint4*)(wt + (size_t)nt * 128 * 256);
#pragma unroll
    for (int i = 0; i < 16; ++i) {
        int o16 = t + i * 256;            // 16B chunk id 0..4095
        int row = o16 >> 5, c = o16 & 31;
        uint4 va = Ag[o16];
        uint4 vb = Bg[o16];
        int sw = c ^ (row & 7);
        *(uint4*)((char*)As + row * 512 + sw * 16) = va;
        *(uint4*)((char*)Bs + row * 512 + sw * 16) = vb;
    }
    __syncthreads();

    int wr = w >> 1, wc = w & 1;
    f32x4 acc[4][4];
#pragma unroll
    for (int mi = 0; mi < 4; ++mi)
#pragma unroll
        for (int ni = 0; ni < 4; ++ni) acc[mi][ni] = (f32x4){0.f, 0.f, 0.f, 0.f};

    int rA = lane & 15;
    int kg = lane >> 4;    // 0..3 -> k-offset group of 8
#pragma unroll
    for (int ks = 0; ks < 8; ++ks) {
        f16x8 af[4], bf[4];
#pragma unroll
        for (int mi = 0; mi < 4; ++mi) {
            int row = wr * 64 + mi * 16 + rA;
            int c = ks * 4 + kg;
            af[mi] = *(const f16x8*)((const char*)As + row * 512 + ((c ^ (row & 7)) * 16));
        }
#pragma unroll
        for (int ni = 0; ni < 4; ++ni) {
            int row = wc * 64 + ni * 16 + rA;
            int c = ks * 4 + kg;
            bf[ni] = *(const f16x8*)((const char*)Bs + row * 512 + ((c ^ (row & 7)) * 16));
        }
#pragma unroll
        for (int mi = 0; mi < 4; ++mi)
#pragma unroll
            for (int ni = 0; ni < 4; ++ni)
                acc[mi][ni] = __builtin_amdgcn_mfma_f32_16x16x32_f16(af[mi], bf[ni], acc[mi][ni], 0, 0, 0);
    }

    // epilogue: C/D layout col=lane&15, row=(lane>>4)*4+q
    int r4 = (lane >> 4) * 4, cc = lane & 15;
    float bv[4];
#pragma unroll
    for (int ni = 0; ni < 4; ++ni) bv[ni] = bias[nt * 128 + wc * 64 + ni * 16 + cc];
#pragma unroll
    for (int mi = 0; mi < 4; ++mi)
#pragma unroll
        for (int ni = 0; ni < 4; ++ni)
#pragma unroll
            for (int q = 0; q < 4; ++q) {
                int grow = mt * 128 + wr * 64 + mi * 16 + r4 + q;
                int gcol = nt * 128 + wc * 64 + ni * 16 + cc;
                xw[(size_t)grow * 1024 + gcol] = (f16)(acc[mi][ni][q] + bv[ni]);
            }
}

// ---------------- recurrence ----------------
__device__ __forceinline__ float fdot2u(u32 u, u32 h, float acc) {
    return __builtin_amdgcn_fdot2(__builtin_bit_cast(f16x2, u),
                                  __builtin_bit_cast(f16x2, h), acc, false);
}
__device__ __forceinline__ float sigm(float x) {
    return 1.0f / (1.0f + __expf(-x));
}
__device__ __forceinline__ float tanh_f(float x) {
    x = fminf(fmaxf(x, -15.0f), 15.0f);
    float e = __expf(2.0f * x);
    return (e - 1.0f) / (e + 1.0f);
}

// ---- R8 = R6 topology + chunk-major U (embrace rematerialization) ----
// R1-R7 evidence: the backend re-loads loop-invariant U from global every
// step rather than holding it (remat-via-spiller; opaque-asm pinning just
// turns it into real scratch spills, R5). R6 paid that as 92 separate
// dword loads/thread/step (pair-major layout scattered each chunk's 4
// dwords 4 KB apart). Chunk-major upk4 makes each reload ONE coalesced
// global_load_dwordx4 (23/thread/step): 4x less VMEM issue, same bytes.
// 1024 thr/WG, one WG per batch, gate=t>>8 (wave-uniform), unit=t&255.
// U chunks 0..22 via remat loads; chunks 23..31 in LDS stride-36
// (SQ_LDS_BANK_CONFLICT measured 0).

#define DECLC(c) uint4 uc_##c;
#define LOADC(c) do { uc_##c = upk4[(c) * 1024 + t]; } while (0)
#define CHR(c) do {                                \
    uint4 hv = *(const uint4*)&hpair[4*(c)];       \
    a0 = fdot2u(uc_##c.x, hv.x, a0);               \
    a1 = fdot2u(uc_##c.y, hv.y, a1);               \
    a2 = fdot2u(uc_##c.z, hv.z, a2);               \
    a3 = fdot2u(uc_##c.w, hv.w, a3);               \
} while (0)

__launch_bounds__(1024)
__global__ void lstm_rec(const uint4* __restrict__ upk4, const f16* __restrict__ xw,
                         float* __restrict__ out) {
    __shared__ __align__(16) u32 ulds[1024 * 36];  // 144 KB: chunks 23..31 per col, stride 36
    __shared__ __align__(16) u32 hpair[128];       // 256 h as f16 pairs
    __shared__ __align__(16) float gbuf[1024];     // activated gates

    int b = blockIdx.x, t = threadIdx.x;

    DECLC(0)  DECLC(1)  DECLC(2)  DECLC(3)  DECLC(4)  DECLC(5)
    DECLC(6)  DECLC(7)  DECLC(8)  DECLC(9)  DECLC(10) DECLC(11)
    DECLC(12) DECLC(13) DECLC(14) DECLC(15) DECLC(16) DECLC(17)
    DECLC(18) DECLC(19) DECLC(20) DECLC(21) DECLC(22)

    LOADC(0);  LOADC(1);  LOADC(2);  LOADC(3);  LOADC(4);  LOADC(5);
    LOADC(6);  LOADC(7);  LOADC(8);  LOADC(9);  LOADC(10); LOADC(11);
    LOADC(12); LOADC(13); LOADC(14); LOADC(15); LOADC(16); LOADC(17);
    LOADC(18); LOADC(19); LOADC(20); LOADC(21); LOADC(22);

#pragma unroll
    for (int ch = 0; ch < 9; ++ch) {
        uint4 v = upk4[(23 + ch) * 1024 + t];
        *(uint4*)&ulds[t * 36 + ch * 4] = v;
    }
    if (t < 128) hpair[t] = 0u;

    float c_state = 0.0f;
    const f16* xp = xw + (size_t)b * SEQT * G4;
    float* op = out + (size_t)b * SEQT * HU;
    f16 xa = xp[t];
    __syncthreads();

    for (int st = 0; st < SEQT; ++st) {
        float a0 = (float)xa, a1 = 0.f, a2 = 0.f, a3 = 0.f;
        if (st < SEQT - 1) xa = xp[G4 + t];   // prefetch next step
        xp += G4;

        // chunks 0..22: U from registers (or cheap dwordx4 remat), h from LDS
        CHR(0);  CHR(1);  CHR(2);  CHR(3);  CHR(4);  CHR(5);
        CHR(6);  CHR(7);  CHR(8);  CHR(9);  CHR(10); CHR(11);
        CHR(12); CHR(13); CHR(14); CHR(15); CHR(16); CHR(17);
        CHR(18); CHR(19); CHR(20); CHR(21); CHR(22);

        // chunks 23..31: U from LDS
#pragma unroll
        for (int ch = 0; ch < 9; ++ch) {
            uint4 hv = *(const uint4*)&hpair[92 + ch * 4];
            uint4 u4 = *(const uint4*)&ulds[t * 36 + ch * 4];
            a0 = fdot2u(u4.x, hv.x, a0);
            a1 = fdot2u(u4.y, hv.y, a1);
            a2 = fdot2u(u4.z, hv.z, a2);
            a3 = fdot2u(u4.w, hv.w, a3);
        }
        float a = (a0 + a1) + (a2 + a3);

        // activation: gate = t>>8 (wave-uniform). g-gate (2) is tanh.
        float act = ((t >> 8) == 2) ? tanh_f(a) : sigm(a);
        gbuf[t] = act;
        __syncthreads();

        if (t < 256) {
            float gi = gbuf[t];
            float gf = gbuf[256 + t];
            float gg = gbuf[512 + t];
            float go = gbuf[768 + t];
            c_state = gf * c_state + gi * gg;
            float h = go * tanh_f(c_state);
            op[t] = h;
            ((f16*)hpair)[t] = (f16)h;
        }
        op += HU;
        __syncthreads();
    }
}

extern "C" void kernel_launch(void* const* d_in, const int* in_sizes, int n_in,
                              void* d_out, int out_size, void* d_ws, size_t ws_size,
                              hipStream_t stream) {
    const float* x    = (const float*)d_in[0];
    const float* W    = (const float*)d_in[1];
    const float* U    = (const float*)d_in[2];
    const float* bias = (const float*)d_in[3];
    float* out = (float*)d_out;

    if (ws_size < WS_NEED) return;  // fail loudly rather than corrupt
    char* ws = (char*)d_ws;
    f16* xw    = (f16*)(ws + WS_XW);
    f16* xh    = (f16*)(ws + WS_XH);
    f16* wt    = (f16*)(ws + WS_WT);
    u32* upk4  = (u32*)(ws + WS_UP);

    pack_u<<<512, 256, 0, stream>>>(U, upk4);
    conv_x<<<8192, 256, 0, stream>>>(x, xh);
    conv_w<<<128, 256, 0, stream>>>(W, wt);
    gemm_xw<<<dim3(512, 8), 256, 0, stream>>>(xh, wt, bias, xw);
    lstm_rec<<<32, 1024, 0, stream>>>((const uint4*)upk4, xw, out);
}